// Round 1
// baseline (117.701 us; speedup 1.0000x reference)
//
#include <hip/hip_runtime.h>
#include <math.h>

#define BATCH 64
#define SEQ   2048
#define HID   1024
#define CHUNKS 16
#define ROWS_PER_BLOCK (SEQ / CHUNKS)            // 128
#define NWAVES 4
#define ROWS_PER_WAVE (ROWS_PER_BLOCK / NWAVES)  // 32
#define PART_STRIDE 1028                         // floats per partial record (16B-aligned stride)

// Pass 1: fused scores + online-softmax context accumulation.
// One read of encoder_outputs total. Each wave owns 32 S-rows.
__global__ __launch_bounds__(256) void attn_pass1(
    const float* __restrict__ dec, const float* __restrict__ enc,
    float* __restrict__ scores, float* __restrict__ partials)
{
    const int b     = blockIdx.x / CHUNKS;
    const int chunk = blockIdx.x % CHUNKS;
    const int tid   = threadIdx.x;
    const int wave  = tid >> 6;
    const int lane  = tid & 63;

    // decoder state resident in registers: lane holds h = p*256 + lane*4 + j
    const float4* decv = reinterpret_cast<const float4*>(dec + b * HID);
    float4 sv[4];
#pragma unroll
    for (int p = 0; p < 4; ++p) sv[p] = decv[p * 64 + lane];

    float m = -1e30f, l = 0.0f;
    float4 c[4];
#pragma unroll
    for (int p = 0; p < 4; ++p) c[p] = make_float4(0.f, 0.f, 0.f, 0.f);

    const int row0 = chunk * ROWS_PER_BLOCK + wave * ROWS_PER_WAVE;
    const float4* encv = reinterpret_cast<const float4*>(enc + (size_t)b * SEQ * HID);

    for (int r = 0; r < ROWS_PER_WAVE; ++r) {
        const int i = row0 + r;
        const float4* rowp = encv + (size_t)i * (HID / 4);
        float4 e[4];
#pragma unroll
        for (int p = 0; p < 4; ++p) e[p] = rowp[p * 64 + lane];

        float dot = 0.f;
#pragma unroll
        for (int p = 0; p < 4; ++p)
            dot += e[p].x * sv[p].x + e[p].y * sv[p].y + e[p].z * sv[p].z + e[p].w * sv[p].w;
#pragma unroll
        for (int off = 32; off > 0; off >>= 1) dot += __shfl_xor(dot, off, 64);

        if (lane == 0) scores[b * SEQ + i] = dot;

        const float mn    = fmaxf(m, dot);
        const float scale = __expf(m - mn);     // first iter: exp(-huge) -> 0
        const float pw    = __expf(dot - mn);
        l = l * scale + pw;
        m = mn;
#pragma unroll
        for (int p = 0; p < 4; ++p) {
            c[p].x = c[p].x * scale + pw * e[p].x;
            c[p].y = c[p].y * scale + pw * e[p].y;
            c[p].z = c[p].z * scale + pw * e[p].z;
            c[p].w = c[p].w * scale + pw * e[p].w;
        }
    }

    // merge the 4 waves' (m,l,c) in LDS, emit one partial per block
    __shared__ float lm[NWAVES], ll[NWAVES];
    __shared__ float lc[NWAVES][HID];
    float4* lcw = reinterpret_cast<float4*>(lc[wave]);
#pragma unroll
    for (int p = 0; p < 4; ++p) lcw[p * 64 + lane] = c[p];
    if (lane == 0) { lm[wave] = m; ll[wave] = l; }
    __syncthreads();

    const float M = fmaxf(fmaxf(lm[0], lm[1]), fmaxf(lm[2], lm[3]));
    float w[NWAVES];
    float L = 0.f;
#pragma unroll
    for (int k = 0; k < NWAVES; ++k) { w[k] = __expf(lm[k] - M); L += ll[k] * w[k]; }

    float4 acc = make_float4(0.f, 0.f, 0.f, 0.f);
#pragma unroll
    for (int k = 0; k < NWAVES; ++k) {
        float4 v = reinterpret_cast<const float4*>(lc[k])[tid];
        acc.x += v.x * w[k]; acc.y += v.y * w[k];
        acc.z += v.z * w[k]; acc.w += v.w * w[k];
    }
    float* rec = partials + (size_t)blockIdx.x * PART_STRIDE;
    reinterpret_cast<float4*>(rec)[tid] = acc;
    if (tid == 0) { rec[HID] = M; rec[HID + 1] = L; }
}

// Pass 2: per batch, merge 16 chunk partials, write context and normalized attn.
__global__ __launch_bounds__(256) void attn_pass2(
    const float* __restrict__ scores, const float* __restrict__ partials,
    float* __restrict__ out_ctx, float* __restrict__ out_attn)
{
    const int b = blockIdx.x;
    const int t = threadIdx.x;

    float mk[CHUNKS], lk[CHUNKS];
    float M = -1e30f;
#pragma unroll
    for (int k = 0; k < CHUNKS; ++k) {
        const float* rec = partials + (size_t)(b * CHUNKS + k) * PART_STRIDE;
        mk[k] = rec[HID];
        lk[k] = rec[HID + 1];
        M = fmaxf(M, mk[k]);
    }
    float L = 0.f;
    float wk[CHUNKS];
#pragma unroll
    for (int k = 0; k < CHUNKS; ++k) { wk[k] = __expf(mk[k] - M); L += lk[k] * wk[k]; }
    const float invL = 1.0f / L;

    float4 acc = make_float4(0.f, 0.f, 0.f, 0.f);
#pragma unroll
    for (int k = 0; k < CHUNKS; ++k) {
        const float4* rec4 =
            reinterpret_cast<const float4*>(partials + (size_t)(b * CHUNKS + k) * PART_STRIDE);
        float4 v = rec4[t];
        acc.x += v.x * wk[k]; acc.y += v.y * wk[k];
        acc.z += v.z * wk[k]; acc.w += v.w * wk[k];
    }
    float4 o;
    o.x = acc.x * invL; o.y = acc.y * invL; o.z = acc.z * invL; o.w = acc.w * invL;
    reinterpret_cast<float4*>(out_ctx + b * HID)[t] = o;

    for (int i = t; i < SEQ; i += 256) {
        out_attn[b * SEQ + i] = __expf(scores[b * SEQ + i] - M) * invL;
    }
}

extern "C" void kernel_launch(void* const* d_in, const int* in_sizes, int n_in,
                              void* d_out, int out_size, void* d_ws, size_t ws_size,
                              hipStream_t stream) {
    const float* dec = (const float*)d_in[0];   // [64, 1024]
    const float* enc = (const float*)d_in[1];   // [64, 2048, 1024]
    float* out = (float*)d_out;                 // context [64,1024] then attn [64,2048]

    float* scores   = (float*)d_ws;                          // 64*2048 floats = 512 KB
    float* partials = scores + BATCH * SEQ;                  // 1024 * 1028 floats ~= 4.2 MB

    attn_pass1<<<BATCH * CHUNKS, 256, 0, stream>>>(dec, enc, scores, partials);
    attn_pass2<<<BATCH, 256, 0, stream>>>(scores, partials, out, out + BATCH * HID);
}

// Round 2
// 100.442 us; speedup vs baseline: 1.1718x; 1.1718x over previous
//
#include <hip/hip_runtime.h>
#include <math.h>

#define BATCH 64
#define SEQ   2048
#define HID   1024
#define CHUNKS 16
#define ROWS_PER_BLOCK (SEQ / CHUNKS)            // 128
#define NWAVES 4
#define ROWS_PER_WAVE (ROWS_PER_BLOCK / NWAVES)  // 32
#define PART_STRIDE 1028

typedef float f32x4 __attribute__((ext_vector_type(4)));

// Pass 1: fused scores + online-softmax context accumulation, single read of enc.
// Depth-2 software pipeline, wave-uniform deferred-max branch, nontemporal loads.
__global__ __launch_bounds__(256, 4) void attn_pass1(
    const float* __restrict__ dec, const float* __restrict__ enc,
    float* __restrict__ scores, float* __restrict__ partials)
{
    const int b     = blockIdx.x / CHUNKS;
    const int chunk = blockIdx.x % CHUNKS;
    const int tid   = threadIdx.x;
    const int wave  = tid >> 6;
    const int lane  = tid & 63;

    // decoder state resident in registers
    const f32x4* decv = reinterpret_cast<const f32x4*>(dec + b * HID);
    f32x4 sv[4];
#pragma unroll
    for (int p = 0; p < 4; ++p) sv[p] = decv[p * 64 + lane];

    float m = -1e30f, l = 0.0f;
    f32x4 c[4];
#pragma unroll
    for (int p = 0; p < 4; ++p) c[p] = (f32x4)(0.0f);

    const int row0 = chunk * ROWS_PER_BLOCK + wave * ROWS_PER_WAVE;
    const f32x4* rowp = reinterpret_cast<const f32x4*>(enc + (size_t)b * SEQ * HID)
                        + (size_t)row0 * (HID / 4) + lane;

    f32x4 eA[4], eB[4];
#pragma unroll
    for (int p = 0; p < 4; ++p) eA[p] = __builtin_nontemporal_load(rowp + p * 64);

    auto process = [&](const f32x4 (&e)[4], int r) {
        float dot = 0.f;
#pragma unroll
        for (int p = 0; p < 4; ++p) {
            dot += e[p].x * sv[p].x; dot += e[p].y * sv[p].y;
            dot += e[p].z * sv[p].z; dot += e[p].w * sv[p].w;
        }
#pragma unroll
        for (int off = 32; off > 0; off >>= 1) dot += __shfl_xor(dot, off, 64);

        if (lane == 0) scores[b * SEQ + row0 + r] = dot;

        if (dot <= m) {              // wave-uniform: dot identical across lanes
            const float pw = __expf(dot - m);
            l += pw;
#pragma unroll
            for (int p = 0; p < 4; ++p) c[p] += pw * e[p];
        } else {                     // rare (~log S times): rescale, pw == 1
            const float sc = __expf(m - dot);   // first row: exp(-huge) = 0
            l = l * sc + 1.0f;
#pragma unroll
            for (int p = 0; p < 4; ++p) c[p] = c[p] * sc + e[p];
            m = dot;
        }
    };

    for (int r = 0; r < ROWS_PER_WAVE; r += 2) {
        const f32x4* rp1 = rowp + (size_t)(r + 1) * (HID / 4);
#pragma unroll
        for (int p = 0; p < 4; ++p) eB[p] = __builtin_nontemporal_load(rp1 + p * 64);

        process(eA, r);

        if (r + 2 < ROWS_PER_WAVE) {
            const f32x4* rp2 = rowp + (size_t)(r + 2) * (HID / 4);
#pragma unroll
            for (int p = 0; p < 4; ++p) eA[p] = __builtin_nontemporal_load(rp2 + p * 64);
        }

        process(eB, r + 1);
    }

    // merge the 4 waves' (m,l,c) in LDS, one partial record per block
    __shared__ float lm[NWAVES], ll[NWAVES];
    __shared__ float lc[NWAVES][HID];
    f32x4* lcw = reinterpret_cast<f32x4*>(lc[wave]);
#pragma unroll
    for (int p = 0; p < 4; ++p) lcw[p * 64 + lane] = c[p];
    if (lane == 0) { lm[wave] = m; ll[wave] = l; }
    __syncthreads();

    const float M = fmaxf(fmaxf(lm[0], lm[1]), fmaxf(lm[2], lm[3]));
    float w[NWAVES];
    float L = 0.f;
#pragma unroll
    for (int k = 0; k < NWAVES; ++k) { w[k] = __expf(lm[k] - M); L += ll[k] * w[k]; }

    f32x4 acc = (f32x4)(0.0f);
#pragma unroll
    for (int k = 0; k < NWAVES; ++k) {
        f32x4 v = reinterpret_cast<const f32x4*>(lc[k])[tid];
        acc += v * w[k];
    }
    float* rec = partials + (size_t)blockIdx.x * PART_STRIDE;
    reinterpret_cast<f32x4*>(rec)[tid] = acc;
    if (tid == 0) { rec[HID] = M; rec[HID + 1] = L; }
}

// Pass 2: per batch, merge 16 chunk partials, write context and normalized attn.
__global__ __launch_bounds__(256) void attn_pass2(
    const float* __restrict__ scores, const float* __restrict__ partials,
    float* __restrict__ out_ctx, float* __restrict__ out_attn)
{
    const int b = blockIdx.x;
    const int t = threadIdx.x;

    float mk[CHUNKS], lk[CHUNKS];
    float M = -1e30f;
#pragma unroll
    for (int k = 0; k < CHUNKS; ++k) {
        const float* rec = partials + (size_t)(b * CHUNKS + k) * PART_STRIDE;
        mk[k] = rec[HID];
        lk[k] = rec[HID + 1];
        M = fmaxf(M, mk[k]);
    }
    float L = 0.f;
    float wk[CHUNKS];
#pragma unroll
    for (int k = 0; k < CHUNKS; ++k) { wk[k] = __expf(mk[k] - M); L += lk[k] * wk[k]; }
    const float invL = 1.0f / L;

    f32x4 acc = (f32x4)(0.0f);
#pragma unroll
    for (int k = 0; k < CHUNKS; ++k) {
        const f32x4* rec4 =
            reinterpret_cast<const f32x4*>(partials + (size_t)(b * CHUNKS + k) * PART_STRIDE);
        acc += rec4[t] * wk[k];
    }
    acc *= invL;
    reinterpret_cast<f32x4*>(out_ctx + b * HID)[t] = acc;

    for (int i = t; i < SEQ; i += 256) {
        out_attn[b * SEQ + i] = __expf(scores[b * SEQ + i] - M) * invL;
    }
}

extern "C" void kernel_launch(void* const* d_in, const int* in_sizes, int n_in,
                              void* d_out, int out_size, void* d_ws, size_t ws_size,
                              hipStream_t stream) {
    const float* dec = (const float*)d_in[0];   // [64, 1024]
    const float* enc = (const float*)d_in[1];   // [64, 2048, 1024]
    float* out = (float*)d_out;                 // context [64,1024] then attn [64,2048]

    float* scores   = (float*)d_ws;
    float* partials = scores + BATCH * SEQ;

    attn_pass1<<<BATCH * CHUNKS, 256, 0, stream>>>(dec, enc, scores, partials);
    attn_pass2<<<BATCH, 256, 0, stream>>>(scores, partials, out, out + BATCH * HID);
}